// Round 5
// baseline (153.659 us; speedup 1.0000x reference)
//
#include <hip/hip_runtime.h>
#include <hip/hip_bf16.h>
#include <cstdint>
#include <cstddef>

// Problem constants
#define BDIM 2
#define SDIM 2048
#define DDIM 1024
#define HN   16
#define HDIM 64

using bf16 = __bf16;
typedef __attribute__((ext_vector_type(8))) __bf16 bf16x8;
typedef __attribute__((ext_vector_type(4))) __bf16 bf16x4;
typedef __attribute__((ext_vector_type(4))) float  f32x4;

#define MFMA16(a, b, c) __builtin_amdgcn_mfma_f32_16x16x32_bf16((a), (b), (c), 0, 0, 0)

#define ASYNC16(g, l)                                                          \
  __builtin_amdgcn_global_load_lds(                                            \
      (const __attribute__((address_space(1))) void*)(g),                      \
      (__attribute__((address_space(3))) void*)(l), 16, 0, 0)

// scale folded into Q rope table: 1/sqrt(64) * log2(e)  (softmax in exp2 domain)
#define QSCALE 0.1803368801111204f

// ---------------------------------------------------------------- conversions
__global__ __launch_bounds__(256) void cvt_bf16(const float* __restrict__ src,
                                                bf16* __restrict__ dst, int n4) {
  int i = blockIdx.x * 256 + threadIdx.x;
  if (i < n4) {
    float4 v = ((const float4*)src)[i];
    bf16x4 o = {(__bf16)v.x, (__bf16)v.y, (__bf16)v.z, (__bf16)v.w};
    *(bf16x4*)(dst + (size_t)i * 4) = o;
  }
}

struct Ptr4 { const float* p[4]; };
// 4 weight matrices -> contiguous bf16 (wq,wk,wv,wo), grid.y = segment
__global__ __launch_bounds__(256) void cvt_w(Ptr4 srcs, bf16* __restrict__ dst) {
  const int seg = blockIdx.y;
  const float* src = srcs.p[seg];
  int i = blockIdx.x * 256 + threadIdx.x;  // < NW/4
  float4 v = ((const float4*)src)[i];
  bf16x4 o = {(__bf16)v.x, (__bf16)v.y, (__bf16)v.z, (__bf16)v.w};
  *(bf16x4*)(dst + (size_t)seg * (DDIM * DDIM) + (size_t)i * 4) = o;
}

// ---------------------------------------------------------------- rope table (packed cos,sin; Q copy pre-scaled)
__global__ __launch_bounds__(256) void rope_table(float2* __restrict__ cq,
                                                  float2* __restrict__ ck) {
  int i = blockIdx.x * 256 + threadIdx.x;  // SDIM*32 threads
  int s = i >> 5, j = i & 31;
  float inv = powf(10000.f, -(float)j * (1.f / 32.f));
  float a = (float)s * inv;
  float sn, c;
  sincosf(a, &sn, &c);
  ck[i] = make_float2(c, sn);
  cq[i] = make_float2(c * QSCALE, sn * QSCALE);
}

// ---------------------------------------------------------------- GEMM  C = A * B^T
// A: [4096][1024] bf16 row-major, Bw: [1024][1024] bf16 row-major (rows = out features)
// MODE 0: z=0 -> Q [bh][s][64] bf16, roped+scaled; z=1 -> K roped; z=2 -> V^T [bh][64][s]
// MODE 1: write fp32 row-major [4096][1024]
template <int MODE>
__global__ __launch_bounds__(256) void gemm_bt(const bf16* __restrict__ A,
                                               const bf16* __restrict__ B0,
                                               void* __restrict__ C0,
                                               const float2* __restrict__ cq,
                                               const float2* __restrict__ ck) {
  constexpr int K = 1024;
  __shared__ __align__(16) bf16 As[128 * 64];
  __shared__ __align__(16) bf16 Bs[128 * 64];
  const int tid = threadIdx.x;
  const int l = tid & 63, w = tid >> 6;
  const int wr = w >> 1, wc = w & 1;
  const int lr = l & 15, lg = l >> 4;
  const int bm = blockIdx.y * 128;
  const int bn = blockIdx.x * 128;
  const bf16* Bw = B0 + (size_t)blockIdx.z * (1024 * 1024);

  f32x4 acc[4][4] = {};

  for (int k0 = 0; k0 < K; k0 += 64) {
    __syncthreads();
#pragma unroll
    for (int i = 0; i < 4; ++i) {
      int idx = i * 2048 + tid * 8;
      int row = idx >> 6, col = idx & 63;
      ASYNC16(A + (size_t)(bm + row) * K + (k0 + col), As + idx);
      ASYNC16(Bw + (size_t)(bn + row) * K + (k0 + col), Bs + idx);
    }
    __syncthreads();
#pragma unroll
    for (int c = 0; c < 2; ++c) {
      bf16x8 af[4], bfr[4];
#pragma unroll
      for (int m = 0; m < 4; ++m)
        af[m] = *(const bf16x8*)(As + (wr * 64 + m * 16 + lr) * 64 + c * 32 + lg * 8);
#pragma unroll
      for (int n = 0; n < 4; ++n)
        bfr[n] = *(const bf16x8*)(Bs + (wc * 64 + n * 16 + lr) * 64 + c * 32 + lg * 8);
      __builtin_amdgcn_s_setprio(1);
#pragma unroll
      for (int m = 0; m < 4; ++m)
#pragma unroll
        for (int n = 0; n < 4; ++n)
          acc[m][n] = MFMA16(af[m], bfr[n], acc[m][n]);
      __builtin_amdgcn_s_setprio(0);
    }
  }

  if constexpr (MODE == 0) {
    const int z = blockIdx.z;
    bf16* C = (bf16*)C0 + (size_t)z * ((size_t)BDIM * SDIM * DDIM);
    if (z == 2) {
      // V^T: [bh][64][2048]; 4 r-values are consecutive s -> bf16x4 store
#pragma unroll
      for (int m = 0; m < 4; ++m)
#pragma unroll
        for (int n = 0; n < 4; ++n) {
          int row0 = bm + wr * 64 + m * 16 + lg * 4;
          int col  = bn + wc * 64 + n * 16 + lr;
          int bb = row0 >> 11, s0 = row0 & (SDIM - 1);
          int h = col >> 6, hd = col & 63;
          bf16x4 pv = {(__bf16)acc[m][n][0], (__bf16)acc[m][n][1],
                       (__bf16)acc[m][n][2], (__bf16)acc[m][n][3]};
          *(bf16x4*)(C + ((size_t)(bb * HN + h) * HDIM + hd) * SDIM + s0) = pv;
        }
    } else {
      // Q/K with fused RoPE: pair frag n (hd=j<32) with n+2 (hd=j+32)
      const float2* tab = z ? ck : cq;
#pragma unroll
      for (int m = 0; m < 4; ++m)
#pragma unroll
        for (int n = 0; n < 2; ++n) {
          int j = n * 16 + lr;            // hd < 32
          int h = (bn >> 6) + wc;         // col>>6 (bn multiple of 128)
#pragma unroll
          for (int r = 0; r < 4; ++r) {
            int row = bm + wr * 64 + m * 16 + lg * 4 + r;
            int s = row & (SDIM - 1), bb = row >> 11;
            float2 cs = tab[s * 32 + j];
            float a = acc[m][n][r], b2 = acc[m][n + 2][r];
            size_t base = ((size_t)(bb * HN + h) * SDIM + s) * HDIM;
            C[base + j]      = (__bf16)(a * cs.x - b2 * cs.y);
            C[base + j + 32] = (__bf16)(b2 * cs.x + a * cs.y);
          }
        }
    }
  } else {
#pragma unroll
    for (int m = 0; m < 4; ++m)
#pragma unroll
      for (int n = 0; n < 4; ++n)
#pragma unroll
        for (int r = 0; r < 4; ++r) {
          int row = bm + wr * 64 + m * 16 + lg * 4 + r;
          int col = bn + wc * 64 + n * 16 + lr;
          ((float*)C0)[(size_t)row * DDIM + col] = acc[m][n][r];
        }
  }
}

// ---------------------------------------------------------------- flash attention (causal, balanced, swapped-QK^T)
// Q/K: [B*H][S][HD] bf16 (roped, Q pre-scaled). Vt: [B*H][HD][S].
// head-major work remap (XCD L2 locality); q-tile pair (qp, 31-qp) = 33 stages;
// double-buffered K/V staging, 1 barrier/tile; lazy cross-lane max (defer-max).
__global__ __launch_bounds__(256) void attn_fwd(const bf16* __restrict__ qg,
                                                const bf16* __restrict__ kg,
                                                const bf16* __restrict__ vtg,
                                                bf16* __restrict__ og) {
  __shared__ __align__(16) bf16 Ks[2][8 * 512];
  __shared__ __align__(16) bf16 Vs[2][8 * 512];
  __shared__ __align__(16) bf16 Pl[4][16 * 72];

  const int tid = threadIdx.x;
  const int l = tid & 63, w = tid >> 6;
  const int lr = l & 15, lg = l >> 4;
  const int lin = blockIdx.x + (blockIdx.y << 4);
  const int bh = lin & 31;   // head-major: lin%8 == head%8 -> 4 heads/XCD
  const int qp = lin >> 5;   // 0..15
  const size_t hb = (size_t)bh * SDIM * HDIM;
  const bf16* Q  = qg + hb;
  const bf16* Kp = kg + hb;
  const bf16* Vp = vtg + hb;  // [64][SDIM]
  const int b = bh >> 4, h = bh & 15;
  bf16* Pw = &Pl[w][0];

  const int mm0 = 2 * w, mm1 = 2 * w + 1;
  const int f0 = mm0 & 3, c0 = mm0 >> 2;
  const int f1 = mm1 & 3, c1 = mm1 >> 2;
  bf16* const kd0_0 = Ks[0] + mm0 * 512 + l * 8;
  bf16* const kd1_0 = Ks[0] + mm1 * 512 + l * 8;
  bf16* const vd0_0 = Vs[0] + mm0 * 512 + l * 8;
  bf16* const vd1_0 = Vs[0] + mm1 * 512 + l * 8;

  for (int phase = 0; phase < 2; ++phase) {
    const int qt = phase ? (31 - qp) : qp;
    const int q0 = qt * 64;

    bf16x8 qf[2];
#pragma unroll
    for (int c = 0; c < 2; ++c)
      qf[c] = *(const bf16x8*)(Q + (size_t)(q0 + w * 16 + lr) * HDIM + c * 32 + lg * 8);

    f32x4 o[4] = {};
    float m = -3e38f, lsum = 0.f;

    // per-lane source pointers, advanced by constant stride per tile
    const bf16* kN0 = Kp + (size_t)(f0 * 16 + lr) * HDIM + c0 * 32 + lg * 8;
    const bf16* kN1 = Kp + (size_t)(f1 * 16 + lr) * HDIM + c1 * 32 + lg * 8;
    const bf16* vN0 = Vp + (size_t)(f0 * 16 + lr) * SDIM + c0 * 32 + lg * 8;
    const bf16* vN1 = Vp + (size_t)(f1 * 16 + lr) * SDIM + c1 * 32 + lg * 8;

    // prologue: stage tile 0 into buffer 0
    ASYNC16(kN0, kd0_0); kN0 += 64 * HDIM;
    ASYNC16(kN1, kd1_0); kN1 += 64 * HDIM;
    ASYNC16(vN0, vd0_0); vN0 += 64;
    ASYNC16(vN1, vd1_0); vN1 += 64;
    __syncthreads();

    for (int t = 0; t <= qt; ++t) {
      const int cur = t & 1;
      // issue next tile's staging into the other buffer (hidden under compute)
      if (t < qt) {
        bf16* kd = Ks[cur ^ 1];
        bf16* vd = Vs[cur ^ 1];
        ASYNC16(kN0, kd + mm0 * 512 + l * 8); kN0 += 64 * HDIM;
        ASYNC16(kN1, kd + mm1 * 512 + l * 8); kN1 += 64 * HDIM;
        ASYNC16(vN0, vd + mm0 * 512 + l * 8); vN0 += 64;
        ASYNC16(vN1, vd + mm1 * 512 + l * 8); vN1 += 64;
      }

      const bool diag = (t == qt);
      const int fLim = diag ? w : 3;

      // swapped QK^T: sc[f] col=q-row(lr), row=key(f*16+lg*4+r)
      f32x4 sc[4] = {};
      __builtin_amdgcn_s_setprio(1);
#pragma unroll
      for (int c = 0; c < 2; ++c)
#pragma unroll
        for (int f = 0; f < 4; ++f)
          if (f <= fLim) {
            bf16x8 kfr = *(const bf16x8*)(Ks[cur] + (c * 4 + f) * 512 + l * 8);
            sc[f] = MFMA16(kfr, qf[c], sc[f]);
          }
      __builtin_amdgcn_s_setprio(0);

      if (diag) {
#pragma unroll
        for (int f = 0; f < 4; ++f)
#pragma unroll
          for (int r = 0; r < 4; ++r) {
            if (f > w)
              sc[f][r] = -3e38f;
            else if (f == w)
              sc[f][r] = (lg * 4 + r <= lr) ? sc[f][r] : -3e38f;
          }
      }

      // per-lane local max drives defer-max; cross-lane reduce only on trigger
      float mxl = -3e38f;
#pragma unroll
      for (int f = 0; f < 4; ++f)
#pragma unroll
        for (int r = 0; r < 4; ++r) mxl = fmaxf(mxl, sc[f][r]);

      if (!__all(mxl - m <= 8.f)) {
        float mx = fmaxf(mxl, __shfl_xor(mxl, 16));
        mx = fmaxf(mx, __shfl_xor(mx, 32));
        float mnew = fmaxf(m, mx);
        float corr = exp2f(m - mnew);
        m = mnew;
        lsum *= corr;
        float cb[4];
#pragma unroll
        for (int r = 0; r < 4; ++r) cb[r] = __shfl(corr, lg * 4 + r);
#pragma unroll
        for (int n = 0; n < 4; ++n)
#pragma unroll
          for (int r = 0; r < 4; ++r) o[n][r] *= cb[r];
      }

      // P = exp2(sc - m); packed b64 stores to Pl[q][key]
      float rs = 0.f;
#pragma unroll
      for (int f = 0; f < 4; ++f) {
        float p0 = exp2f(sc[f][0] - m);
        float p1 = exp2f(sc[f][1] - m);
        float p2 = exp2f(sc[f][2] - m);
        float p3 = exp2f(sc[f][3] - m);
        rs += (p0 + p1) + (p2 + p3);
        bf16x4 pv = {(__bf16)p0, (__bf16)p1, (__bf16)p2, (__bf16)p3};
        *(bf16x4*)(Pw + lr * 72 + f * 16 + lg * 4) = pv;
      }
      rs += __shfl_xor(rs, 16);
      rs += __shfl_xor(rs, 32);
      lsum += rs;

      // PV (skip fully-zero key chunks on the diagonal tile)
      const int cLim = diag ? (w >> 1) : 1;
      __builtin_amdgcn_s_setprio(1);
#pragma unroll
      for (int c = 0; c < 2; ++c)
        if (c <= cLim) {
          bf16x8 pf = *(const bf16x8*)(Pw + lr * 72 + c * 32 + lg * 8);
#pragma unroll
          for (int n = 0; n < 4; ++n) {
            bf16x8 vfr = *(const bf16x8*)(Vs[cur] + (c * 4 + n) * 512 + l * 8);
            o[n] = MFMA16(pf, vfr, o[n]);
          }
        }
      __builtin_amdgcn_s_setprio(0);

      __syncthreads();  // buf[cur] consumed by all; buf[cur^1] staged+visible
    }

    // epilogue: broadcast lsum from softmax layout (per lr) to O layout (per lg*4+r)
    float lb[4];
#pragma unroll
    for (int r = 0; r < 4; ++r) lb[r] = __shfl(lsum, lg * 4 + r);
#pragma unroll
    for (int r = 0; r < 4; ++r) {
      float rl = 1.f / lb[r];
      int qr = q0 + 16 * w + lg * 4 + r;
#pragma unroll
      for (int n = 0; n < 4; ++n)
        og[((size_t)(b * SDIM + qr)) * DDIM + h * HDIM + n * 16 + lr] =
            (__bf16)(o[n][r] * rl);
    }
  }
}

// ---------------------------------------------------------------- launch
extern "C" void kernel_launch(void* const* d_in, const int* in_sizes, int n_in,
                              void* d_out, int out_size, void* d_ws, size_t ws_size,
                              hipStream_t stream) {
  const float* x  = (const float*)d_in[0];
  const float* wq = (const float*)d_in[1];
  const float* wk = (const float*)d_in[2];
  const float* wv = (const float*)d_in[3];
  const float* wo = (const float*)d_in[4];

  char* ws = (char*)d_ws;
  const size_t MB = 1024 * 1024;
  bf16* xb   = (bf16*)(ws + 0);        // 8 MB  (A for QKV gemm)
  bf16* wqb  = (bf16*)(ws + 8 * MB);   // wq,wk,wv,wo contiguous (2 MB each)
  bf16* wob  = (bf16*)(ws + 14 * MB);
  bf16* qb   = (bf16*)(ws + 16 * MB);  // Q [bh][s][64]
  bf16* kb   = (bf16*)(ws + 24 * MB);  // K [bh][s][64]
  bf16* vtb  = (bf16*)(ws + 32 * MB);  // V^T [bh][64][s] (written directly by gemm z=2)
  bf16* ob   = (bf16*)(ws + 40 * MB);  // attention output [B][S][D]
  float2* cqT = (float2*)(ws + 48 * MB);  // 512 KB (cos,sin)*QSCALE
  float2* ckT = (float2*)(ws + 48 * MB + 512 * 1024);  // 512 KB (cos,sin)

  const int NX = BDIM * SDIM * DDIM;  // 4194304
  const int NW = DDIM * DDIM;         // 1048576

  cvt_bf16<<<NX / 4 / 256, 256, 0, stream>>>(x, xb, NX / 4);
  Ptr4 wsrc{{wq, wk, wv, wo}};
  cvt_w<<<dim3(NW / 4 / 256, 4), 256, 0, stream>>>(wsrc, wqb);
  rope_table<<<(SDIM * 32) / 256, 256, 0, stream>>>(cqT, ckT);
  gemm_bt<0><<<dim3(8, 32, 3), 256, 0, stream>>>(xb, wqb, (void*)qb, cqT, ckT);
  attn_fwd<<<dim3(16, 32), 256, 0, stream>>>(qb, kb, vtb, ob);
  gemm_bt<1><<<dim3(8, 32, 1), 256, 0, stream>>>(ob, wob, d_out, nullptr, nullptr);
}

// Round 6
// 145.824 us; speedup vs baseline: 1.0537x; 1.0537x over previous
//
#include <hip/hip_runtime.h>
#include <hip/hip_bf16.h>
#include <cstdint>
#include <cstddef>

// Problem constants
#define BDIM 2
#define SDIM 2048
#define DDIM 1024
#define HN   16
#define HDIM 64

using bf16 = __bf16;
typedef __attribute__((ext_vector_type(8))) __bf16 bf16x8;
typedef __attribute__((ext_vector_type(4))) __bf16 bf16x4;
typedef __attribute__((ext_vector_type(8))) unsigned short ushort8;
typedef __attribute__((ext_vector_type(4))) float  f32x4;

#define MFMA16(a, b, c) __builtin_amdgcn_mfma_f32_16x16x32_bf16((a), (b), (c), 0, 0, 0)

#define ASYNC16(g, l)                                                          \
  __builtin_amdgcn_global_load_lds(                                            \
      (const __attribute__((address_space(1))) void*)(g),                      \
      (__attribute__((address_space(3))) void*)(l), 16, 0, 0)

// scale folded into Q at rope time: 1/sqrt(64) * log2(e)  (softmax in exp2 domain)
#define QSCALE 0.1803368801111204f

// ---------------------------------------------------------------- conversions
__global__ __launch_bounds__(256) void cvt_bf16(const float* __restrict__ src,
                                                bf16* __restrict__ dst, int n4) {
  int i = blockIdx.x * 256 + threadIdx.x;
  if (i < n4) {
    float4 v = ((const float4*)src)[i];
    bf16x4 o = {(__bf16)v.x, (__bf16)v.y, (__bf16)v.z, (__bf16)v.w};
    *(bf16x4*)(dst + (size_t)i * 4) = o;
  }
}

struct Ptr4 { const float* p[4]; };
// 4 weight matrices -> contiguous bf16 (wq,wk,wv,wo), grid.y = segment
__global__ __launch_bounds__(256) void cvt_w(Ptr4 srcs, bf16* __restrict__ dst) {
  const int seg = blockIdx.y;
  const float* src = srcs.p[seg];
  int i = blockIdx.x * 256 + threadIdx.x;  // < NW/4
  float4 v = ((const float4*)src)[i];
  bf16x4 o = {(__bf16)v.x, (__bf16)v.y, (__bf16)v.z, (__bf16)v.w};
  *(bf16x4*)(dst + (size_t)seg * (DDIM * DDIM) + (size_t)i * 4) = o;
}

// ---------------------------------------------------------------- rope table
__global__ __launch_bounds__(256) void rope_table(float* __restrict__ cosT,
                                                  float* __restrict__ sinT) {
  int i = blockIdx.x * 256 + threadIdx.x;  // SDIM*32 threads
  int s = i >> 5, j = i & 31;
  float inv = powf(10000.f, -(float)j * (1.f / 32.f));
  float a = (float)s * inv;
  float sn, c;
  sincosf(a, &sn, &c);
  cosT[s * 64 + j]      = c;
  cosT[s * 64 + j + 32] = c;
  sinT[s * 64 + j]      = sn;
  sinT[s * 64 + j + 32] = sn;
}

// ---------------------------------------------------------------- rope apply (in-place; q also pre-scaled)
__global__ __launch_bounds__(256) void rope_apply(bf16* __restrict__ q,
                                                  bf16* __restrict__ k,
                                                  const float* __restrict__ cosT,
                                                  const float* __restrict__ sinT) {
  int i = blockIdx.x * 256 + threadIdx.x;  // 32*SDIM*32 threads
  int j = i & 31;
  int s = (i >> 5) & (SDIM - 1);
  int bh = i >> 16;  // SDIM*32 == 1<<16
  size_t base = ((size_t)bh * SDIM + s) * HDIM;
  float c = cosT[s * 64 + j], sn = sinT[s * 64 + j];
  float a = (float)q[base + j], b2 = (float)q[base + j + 32];
  q[base + j]      = (__bf16)((a * c - b2 * sn) * QSCALE);
  q[base + j + 32] = (__bf16)((b2 * c + a * sn) * QSCALE);
  a = (float)k[base + j]; b2 = (float)k[base + j + 32];
  k[base + j]      = (__bf16)(a * c - b2 * sn);
  k[base + j + 32] = (__bf16)(b2 * c + a * sn);
}

// ---------------------------------------------------------------- V transpose: [bh][s][64] -> [bh][64][s]
__global__ __launch_bounds__(256) void transpose_v(const unsigned short* __restrict__ v,
                                                   unsigned short* __restrict__ vt) {
  const int bh = blockIdx.y;
  const int s_base = blockIdx.x * 32 + (threadIdx.x >> 6) * 8;
  const int d = threadIdx.x & 63;
  const unsigned short* src = v + ((size_t)bh * SDIM + s_base) * HDIM + d;
  ushort8 o;
#pragma unroll
  for (int j = 0; j < 8; ++j) o[j] = src[(size_t)j * HDIM];  // coalesced: 64 lanes x 2B = 128B/line
  *(ushort8*)(vt + ((size_t)bh * HDIM + d) * SDIM + s_base) = o;
}

// ---------------------------------------------------------------- GEMM  C = A * B^T
// A: [4096][1024] bf16 row-major, Bw: [1024][1024] bf16 row-major (rows = out features)
// MODE 0: write bf16 to [B][H][S][HD] (QKV), blockIdx.z selects weight/output
// MODE 1: write fp32 row-major [4096][1024]
template <int MODE>
__global__ __launch_bounds__(256) void gemm_bt(const bf16* __restrict__ A,
                                               const bf16* __restrict__ B0,
                                               void* __restrict__ C0) {
  constexpr int K = 1024;
  __shared__ __align__(16) bf16 As[128 * 64];
  __shared__ __align__(16) bf16 Bs[128 * 64];
  const int tid = threadIdx.x;
  const int l = tid & 63, w = tid >> 6;
  const int wr = w >> 1, wc = w & 1;
  const int lr = l & 15, lg = l >> 4;
  const int bm = blockIdx.y * 128;
  const int bn = blockIdx.x * 128;
  const bf16* Bw = B0 + (size_t)blockIdx.z * (1024 * 1024);

  f32x4 acc[4][4] = {};

  for (int k0 = 0; k0 < K; k0 += 64) {
    __syncthreads();
#pragma unroll
    for (int i = 0; i < 4; ++i) {
      int idx = i * 2048 + tid * 8;
      int row = idx >> 6, col = idx & 63;
      ASYNC16(A + (size_t)(bm + row) * K + (k0 + col), As + idx);
      ASYNC16(Bw + (size_t)(bn + row) * K + (k0 + col), Bs + idx);
    }
    __syncthreads();
#pragma unroll
    for (int c = 0; c < 2; ++c) {
      bf16x8 af[4], bfr[4];
#pragma unroll
      for (int m = 0; m < 4; ++m)
        af[m] = *(const bf16x8*)(As + (wr * 64 + m * 16 + lr) * 64 + c * 32 + lg * 8);
#pragma unroll
      for (int n = 0; n < 4; ++n)
        bfr[n] = *(const bf16x8*)(Bs + (wc * 64 + n * 16 + lr) * 64 + c * 32 + lg * 8);
      __builtin_amdgcn_s_setprio(1);
#pragma unroll
      for (int m = 0; m < 4; ++m)
#pragma unroll
        for (int n = 0; n < 4; ++n)
          acc[m][n] = MFMA16(af[m], bfr[n], acc[m][n]);
      __builtin_amdgcn_s_setprio(0);
    }
  }

#pragma unroll
  for (int m = 0; m < 4; ++m) {
#pragma unroll
    for (int n = 0; n < 4; ++n) {
#pragma unroll
      for (int r = 0; r < 4; ++r) {
        int row = bm + wr * 64 + m * 16 + lg * 4 + r;
        int col = bn + wc * 64 + n * 16 + lr;
        float v = acc[m][n][r];
        if constexpr (MODE == 0) {
          bf16* C = (bf16*)C0 + (size_t)blockIdx.z * ((size_t)BDIM * SDIM * DDIM);
          size_t off = (((size_t)(row >> 11) * HN + (col >> 6)) * SDIM + (row & (SDIM - 1))) * HDIM + (col & 63);
          C[off] = (__bf16)v;
        } else {
          ((float*)C0)[(size_t)row * DDIM + col] = v;
        }
      }
    }
  }
}

// ---------------------------------------------------------------- flash attention (causal, swapped-QK^T, unpaired)
// Q/K: [B*H][S][HD] bf16 (roped, Q pre-scaled). Vt: [B*H][HD][S].
// Grid 32x32: x = head (XCD-local, lin%8==head%8), y -> qt = 31-y so the
// longest blocks dispatch first. 1024 blocks; LDS exactly 40 KB -> 4 blocks/CU
// (16 waves/CU vs 8 before). Double-buffered K/V staging, 1 barrier/tile;
// lazy cross-lane max (defer-max); P buffer XOR-chunk-swizzled (no pad).
__global__ __launch_bounds__(256) void attn_fwd(const bf16* __restrict__ qg,
                                                const bf16* __restrict__ kg,
                                                const bf16* __restrict__ vtg,
                                                bf16* __restrict__ og) {
  __shared__ __align__(16) bf16 Ks[2][8 * 512];
  __shared__ __align__(16) bf16 Vs[2][8 * 512];
  __shared__ __align__(16) bf16 Pl[4][16 * 64];  // stride 64, XOR-swizzled chunks

  const int tid = threadIdx.x;
  const int l = tid & 63, w = tid >> 6;
  const int lr = l & 15, lg = l >> 4;
  const int bh = blockIdx.x;          // head-major: 4 heads per XCD
  const int qt = 31 - blockIdx.y;     // largest work first
  const int q0 = qt * 64;
  const size_t hb = (size_t)bh * SDIM * HDIM;
  const bf16* Q  = qg + hb;
  const bf16* Kp = kg + hb;
  const bf16* Vp = vtg + hb;  // [64][SDIM]
  const int b = bh >> 4, h = bh & 15;
  bf16* Pw = &Pl[w][0];
  const int swz = lr & 7;

  const int mm0 = 2 * w, mm1 = 2 * w + 1;
  const int f0 = mm0 & 3, c0 = mm0 >> 2;
  const int f1 = mm1 & 3, c1 = mm1 >> 2;

  bf16x8 qf[2];
#pragma unroll
  for (int c = 0; c < 2; ++c)
    qf[c] = *(const bf16x8*)(Q + (size_t)(q0 + w * 16 + lr) * HDIM + c * 32 + lg * 8);

  f32x4 o[4] = {};
  float m = -3e38f, lsum = 0.f;

  // per-lane source pointers, advanced by constant stride per tile
  const bf16* kN0 = Kp + (size_t)(f0 * 16 + lr) * HDIM + c0 * 32 + lg * 8;
  const bf16* kN1 = Kp + (size_t)(f1 * 16 + lr) * HDIM + c1 * 32 + lg * 8;
  const bf16* vN0 = Vp + (size_t)(f0 * 16 + lr) * SDIM + c0 * 32 + lg * 8;
  const bf16* vN1 = Vp + (size_t)(f1 * 16 + lr) * SDIM + c1 * 32 + lg * 8;

  // prologue: stage tile 0 into buffer 0
  ASYNC16(kN0, Ks[0] + mm0 * 512 + l * 8); kN0 += 64 * HDIM;
  ASYNC16(kN1, Ks[0] + mm1 * 512 + l * 8); kN1 += 64 * HDIM;
  ASYNC16(vN0, Vs[0] + mm0 * 512 + l * 8); vN0 += 64;
  ASYNC16(vN1, Vs[0] + mm1 * 512 + l * 8); vN1 += 64;
  __syncthreads();

  for (int t = 0; t <= qt; ++t) {
    const int cur = t & 1;
    // issue next tile's staging into the other buffer (hidden under compute)
    if (t < qt) {
      bf16* kd = Ks[cur ^ 1];
      bf16* vd = Vs[cur ^ 1];
      ASYNC16(kN0, kd + mm0 * 512 + l * 8); kN0 += 64 * HDIM;
      ASYNC16(kN1, kd + mm1 * 512 + l * 8); kN1 += 64 * HDIM;
      ASYNC16(vN0, vd + mm0 * 512 + l * 8); vN0 += 64;
      ASYNC16(vN1, vd + mm1 * 512 + l * 8); vN1 += 64;
    }

    const bool diag = (t == qt);
    const int fLim = diag ? w : 3;

    // swapped QK^T: sc[f] col=q-row(lr), row=key(f*16+lg*4+r)
    f32x4 sc[4] = {};
    __builtin_amdgcn_s_setprio(1);
#pragma unroll
    for (int c = 0; c < 2; ++c)
#pragma unroll
      for (int f = 0; f < 4; ++f)
        if (f <= fLim) {
          bf16x8 kfr = *(const bf16x8*)(Ks[cur] + (c * 4 + f) * 512 + l * 8);
          sc[f] = MFMA16(kfr, qf[c], sc[f]);
        }
    __builtin_amdgcn_s_setprio(0);

    if (diag) {
#pragma unroll
      for (int f = 0; f < 4; ++f)
#pragma unroll
        for (int r = 0; r < 4; ++r) {
          if (f > w)
            sc[f][r] = -3e38f;
          else if (f == w)
            sc[f][r] = (lg * 4 + r <= lr) ? sc[f][r] : -3e38f;
        }
    }

    // per-lane local max drives defer-max; cross-lane reduce only on trigger
    float mxl = -3e38f;
#pragma unroll
    for (int f = 0; f < 4; ++f)
#pragma unroll
      for (int r = 0; r < 4; ++r) mxl = fmaxf(mxl, sc[f][r]);

    if (!__all(mxl - m <= 8.f)) {
      float mx = fmaxf(mxl, __shfl_xor(mxl, 16));
      mx = fmaxf(mx, __shfl_xor(mx, 32));
      float mnew = fmaxf(m, mx);
      float corr = exp2f(m - mnew);
      m = mnew;
      lsum *= corr;
      float cb[4];
#pragma unroll
      for (int r = 0; r < 4; ++r) cb[r] = __shfl(corr, lg * 4 + r);
#pragma unroll
      for (int n = 0; n < 4; ++n)
#pragma unroll
        for (int r = 0; r < 4; ++r) o[n][r] *= cb[r];
    }

    // P = exp2(sc - m); packed b64 stores into swizzled chunks:
    // element e of row lr lives at chunk (e>>3)^swz, offset e&7
    float rs = 0.f;
#pragma unroll
    for (int f = 0; f < 4; ++f) {
      float p0 = exp2f(sc[f][0] - m);
      float p1 = exp2f(sc[f][1] - m);
      float p2 = exp2f(sc[f][2] - m);
      float p3 = exp2f(sc[f][3] - m);
      rs += (p0 + p1) + (p2 + p3);
      bf16x4 pv = {(__bf16)p0, (__bf16)p1, (__bf16)p2, (__bf16)p3};
      const int ch = f * 2 + (lg >> 1);
      *(bf16x4*)(Pw + lr * 64 + ((ch ^ swz) << 3) + (lg & 1) * 4) = pv;
    }
    rs += __shfl_xor(rs, 16);
    rs += __shfl_xor(rs, 32);
    lsum += rs;

    // PV (skip fully-zero key chunks on the diagonal tile)
    const int cLim = diag ? (w >> 1) : 1;
    __builtin_amdgcn_s_setprio(1);
#pragma unroll
    for (int c = 0; c < 2; ++c)
      if (c <= cLim) {
        bf16x8 pf = *(const bf16x8*)(Pw + lr * 64 + (((c * 4 + lg) ^ swz) << 3));
#pragma unroll
        for (int n = 0; n < 4; ++n) {
          bf16x8 vfr = *(const bf16x8*)(Vs[cur] + (c * 4 + n) * 512 + l * 8);
          o[n] = MFMA16(pf, vfr, o[n]);
        }
      }
    __builtin_amdgcn_s_setprio(0);

    __syncthreads();  // buf[cur] consumed by all; buf[cur^1] staged+visible
  }

  // epilogue: broadcast lsum from softmax layout (per lr) to O layout (per lg*4+r)
  float lb[4];
#pragma unroll
  for (int r = 0; r < 4; ++r) lb[r] = __shfl(lsum, lg * 4 + r);
#pragma unroll
  for (int r = 0; r < 4; ++r) {
    float rl = 1.f / lb[r];
    int qr = q0 + 16 * w + lg * 4 + r;
#pragma unroll
    for (int n = 0; n < 4; ++n)
      og[((size_t)(b * SDIM + qr)) * DDIM + h * HDIM + n * 16 + lr] =
          (__bf16)(o[n][r] * rl);
  }
}

// ---------------------------------------------------------------- launch
extern "C" void kernel_launch(void* const* d_in, const int* in_sizes, int n_in,
                              void* d_out, int out_size, void* d_ws, size_t ws_size,
                              hipStream_t stream) {
  const float* x  = (const float*)d_in[0];
  const float* wq = (const float*)d_in[1];
  const float* wk = (const float*)d_in[2];
  const float* wv = (const float*)d_in[3];
  const float* wo = (const float*)d_in[4];

  char* ws = (char*)d_ws;
  const size_t MB = 1024 * 1024;
  bf16* xb   = (bf16*)(ws + 0);        // 8 MB (reused as vtb after QKV GEMM)
  bf16* wqb  = (bf16*)(ws + 8 * MB);   // wq,wk,wv,wo contiguous (2 MB each)
  bf16* wob  = (bf16*)(ws + 14 * MB);
  bf16* qb   = (bf16*)(ws + 16 * MB);  // Q [bh][s][64]
  bf16* kb   = (bf16*)(ws + 24 * MB);  // K [bh][s][64]
  bf16* vb   = (bf16*)(ws + 32 * MB);  // V [bh][s][64]
  bf16* ob   = (bf16*)(ws + 40 * MB);  // attention output [B][S][D]
  float* cosT = (float*)(ws + 48 * MB);
  float* sinT = (float*)(ws + 49 * MB);
  bf16* vtb  = xb;  // V transposed [bh][64][S], overwrites xb (free after QKV GEMM)

  const int NX = BDIM * SDIM * DDIM;  // 4194304
  const int NW = DDIM * DDIM;         // 1048576

  cvt_bf16<<<NX / 4 / 256, 256, 0, stream>>>(x, xb, NX / 4);
  Ptr4 wsrc{{wq, wk, wv, wo}};
  cvt_w<<<dim3(NW / 4 / 256, 4), 256, 0, stream>>>(wsrc, wqb);
  rope_table<<<(SDIM * 32) / 256, 256, 0, stream>>>(cosT, sinT);
  gemm_bt<0><<<dim3(8, 32, 3), 256, 0, stream>>>(xb, wqb, (void*)qb);
  rope_apply<<<(32 * SDIM * 32) / 256, 256, 0, stream>>>(qb, kb, cosT, sinT);
  transpose_v<<<dim3(SDIM / 32, 32), 256, 0, stream>>>((const unsigned short*)vb,
                                                       (unsigned short*)vtb);
  attn_fwd<<<dim3(32, 32), 256, 0, stream>>>(qb, kb, vtb, ob);
  gemm_bt<1><<<dim3(8, 32, 1), 256, 0, stream>>>(ob, wob, d_out);
}

// Round 7
// 142.481 us; speedup vs baseline: 1.0785x; 1.0235x over previous
//
#include <hip/hip_runtime.h>
#include <hip/hip_bf16.h>
#include <cstdint>
#include <cstddef>

// Problem constants
#define BDIM 2
#define SDIM 2048
#define DDIM 1024
#define HN   16
#define HDIM 64

using bf16 = __bf16;
typedef __attribute__((ext_vector_type(8))) __bf16 bf16x8;
typedef __attribute__((ext_vector_type(4))) __bf16 bf16x4;
typedef __attribute__((ext_vector_type(8))) unsigned short ushort8;
typedef __attribute__((ext_vector_type(4))) float  f32x4;

#define MFMA16(a, b, c) __builtin_amdgcn_mfma_f32_16x16x32_bf16((a), (b), (c), 0, 0, 0)

#define ASYNC16(g, l)                                                          \
  __builtin_amdgcn_global_load_lds(                                            \
      (const __attribute__((address_space(1))) void*)(g),                      \
      (__attribute__((address_space(3))) void*)(l), 16, 0, 0)

// scale folded into Q at rope time: 1/sqrt(64) * log2(e)  (softmax in exp2 domain)
#define QSCALE 0.1803368801111204f

// ---------------------------------------------------------------- conversions
__global__ __launch_bounds__(256) void cvt_bf16(const float* __restrict__ src,
                                                bf16* __restrict__ dst, int n4) {
  int i = blockIdx.x * 256 + threadIdx.x;
  if (i < n4) {
    float4 v = ((const float4*)src)[i];
    bf16x4 o = {(__bf16)v.x, (__bf16)v.y, (__bf16)v.z, (__bf16)v.w};
    *(bf16x4*)(dst + (size_t)i * 4) = o;
  }
}

struct Ptr4 { const float* p[4]; };
// 4 weight matrices -> contiguous bf16 (wq,wk,wv,wo), grid.y = segment
__global__ __launch_bounds__(256) void cvt_w(Ptr4 srcs, bf16* __restrict__ dst) {
  const int seg = blockIdx.y;
  const float* src = srcs.p[seg];
  int i = blockIdx.x * 256 + threadIdx.x;  // < NW/4
  float4 v = ((const float4*)src)[i];
  bf16x4 o = {(__bf16)v.x, (__bf16)v.y, (__bf16)v.z, (__bf16)v.w};
  *(bf16x4*)(dst + (size_t)seg * (DDIM * DDIM) + (size_t)i * 4) = o;
}

// ---------------------------------------------------------------- rope table
__global__ __launch_bounds__(256) void rope_table(float* __restrict__ cosT,
                                                  float* __restrict__ sinT) {
  int i = blockIdx.x * 256 + threadIdx.x;  // SDIM*32 threads
  int s = i >> 5, j = i & 31;
  float inv = powf(10000.f, -(float)j * (1.f / 32.f));
  float a = (float)s * inv;
  float sn, c;
  sincosf(a, &sn, &c);
  cosT[s * 64 + j]      = c;
  cosT[s * 64 + j + 32] = c;
  sinT[s * 64 + j]      = sn;
  sinT[s * 64 + j + 32] = sn;
}

// ---------------------------------------------------------------- fused: rope(q,k) + transpose(v)
// One block = 32 s-rows of one (b,h). Rope is vectorized bf16x4; V transpose
// keeps the coalesced 128B-row gather / ushort8 store pattern.
__global__ __launch_bounds__(256) void fixup_qkv(bf16* __restrict__ q,
                                                 bf16* __restrict__ k,
                                                 const unsigned short* __restrict__ v,
                                                 unsigned short* __restrict__ vt,
                                                 const float* __restrict__ cosT,
                                                 const float* __restrict__ sinT) {
  const int bh = blockIdx.y;
  const int s0 = blockIdx.x * 32;
  const int tid = threadIdx.x;

  // ---- rope on q and k: thread -> (s, 4-wide j group)
  {
    const int s = s0 + (tid >> 3);
    const int j0 = (tid & 7) * 4;
    const size_t base = ((size_t)bh * SDIM + s) * HDIM;
    const float4 c4 = *(const float4*)(cosT + s * 64 + j0);
    const float4 s4 = *(const float4*)(sinT + s * 64 + j0);
    const float cc[4] = {c4.x, c4.y, c4.z, c4.w};
    const float ss[4] = {s4.x, s4.y, s4.z, s4.w};

    bf16x4 qlo = *(bf16x4*)(q + base + j0);
    bf16x4 qhi = *(bf16x4*)(q + base + j0 + 32);
    bf16x4 klo = *(bf16x4*)(k + base + j0);
    bf16x4 khi = *(bf16x4*)(k + base + j0 + 32);
    bf16x4 rql, rqh, rkl, rkh;
#pragma unroll
    for (int e = 0; e < 4; ++e) {
      float a = (float)qlo[e], b = (float)qhi[e];
      rql[e] = (__bf16)((a * cc[e] - b * ss[e]) * QSCALE);
      rqh[e] = (__bf16)((b * cc[e] + a * ss[e]) * QSCALE);
      a = (float)klo[e]; b = (float)khi[e];
      rkl[e] = (__bf16)(a * cc[e] - b * ss[e]);
      rkh[e] = (__bf16)(b * cc[e] + a * ss[e]);
    }
    *(bf16x4*)(q + base + j0)      = rql;
    *(bf16x4*)(q + base + j0 + 32) = rqh;
    *(bf16x4*)(k + base + j0)      = rkl;
    *(bf16x4*)(k + base + j0 + 32) = rkh;
  }

  // ---- v transpose: [bh][s][64] -> [bh][64][s]
  {
    const int w = tid >> 6, d = tid & 63;
    const int sb = s0 + w * 8;
    const unsigned short* src = v + ((size_t)bh * SDIM + sb) * HDIM + d;
    ushort8 o;
#pragma unroll
    for (int j = 0; j < 8; ++j) o[j] = src[(size_t)j * HDIM];
    *(ushort8*)(vt + ((size_t)bh * HDIM + d) * SDIM + sb) = o;
  }
}

// ---------------------------------------------------------------- GEMM  C = A * B^T
// A: [4096][1024] bf16 row-major, Bw: [1024][1024] bf16 row-major (rows = out features)
// MODE 0: write bf16 to [B][H][S][HD] (QKV), blockIdx.z selects weight/output
// MODE 1: write fp32 row-major [4096][1024]
template <int MODE>
__global__ __launch_bounds__(256) void gemm_bt(const bf16* __restrict__ A,
                                               const bf16* __restrict__ B0,
                                               void* __restrict__ C0) {
  constexpr int K = 1024;
  __shared__ __align__(16) bf16 As[128 * 64];
  __shared__ __align__(16) bf16 Bs[128 * 64];
  const int tid = threadIdx.x;
  const int l = tid & 63, w = tid >> 6;
  const int wr = w >> 1, wc = w & 1;
  const int lr = l & 15, lg = l >> 4;
  const int bm = blockIdx.y * 128;
  const int bn = blockIdx.x * 128;
  const bf16* Bw = B0 + (size_t)blockIdx.z * (1024 * 1024);

  f32x4 acc[4][4] = {};

  for (int k0 = 0; k0 < K; k0 += 64) {
    __syncthreads();
#pragma unroll
    for (int i = 0; i < 4; ++i) {
      int idx = i * 2048 + tid * 8;
      int row = idx >> 6, col = idx & 63;
      ASYNC16(A + (size_t)(bm + row) * K + (k0 + col), As + idx);
      ASYNC16(Bw + (size_t)(bn + row) * K + (k0 + col), Bs + idx);
    }
    __syncthreads();
#pragma unroll
    for (int c = 0; c < 2; ++c) {
      bf16x8 af[4], bfr[4];
#pragma unroll
      for (int m = 0; m < 4; ++m)
        af[m] = *(const bf16x8*)(As + (wr * 64 + m * 16 + lr) * 64 + c * 32 + lg * 8);
#pragma unroll
      for (int n = 0; n < 4; ++n)
        bfr[n] = *(const bf16x8*)(Bs + (wc * 64 + n * 16 + lr) * 64 + c * 32 + lg * 8);
      __builtin_amdgcn_s_setprio(1);
#pragma unroll
      for (int m = 0; m < 4; ++m)
#pragma unroll
        for (int n = 0; n < 4; ++n)
          acc[m][n] = MFMA16(af[m], bfr[n], acc[m][n]);
      __builtin_amdgcn_s_setprio(0);
    }
  }

#pragma unroll
  for (int m = 0; m < 4; ++m) {
#pragma unroll
    for (int n = 0; n < 4; ++n) {
#pragma unroll
      for (int r = 0; r < 4; ++r) {
        int row = bm + wr * 64 + m * 16 + lg * 4 + r;
        int col = bn + wc * 64 + n * 16 + lr;
        float v = acc[m][n][r];
        if constexpr (MODE == 0) {
          bf16* C = (bf16*)C0 + (size_t)blockIdx.z * ((size_t)BDIM * SDIM * DDIM);
          size_t off = (((size_t)(row >> 11) * HN + (col >> 6)) * SDIM + (row & (SDIM - 1))) * HDIM + (col & 63);
          C[off] = (__bf16)v;
        } else {
          ((float*)C0)[(size_t)row * DDIM + col] = v;
        }
      }
    }
  }
}

// ---------------------------------------------------------------- flash attention (causal, swapped-QK^T, 3-slot)
// Q/K: [B*H][S][HD] bf16 (roped, Q pre-scaled). Vt: [B*H][HD][S].
// Grid 32x32: x = head (XCD-local), y -> qt = 31-y (largest work first).
// LDS = 3 rotating 8KB K/V slots + 8KB P = 32 KB -> 4 blocks/CU (16 waves).
// Per tile: stage K(t+1)->free slot; QK^T(slot ks); barrier; stage V(t+1)->
// slot ks (now free); softmax+PV(slot vs); barrier; rotate (vs=ks, ks=kn).
__global__ __launch_bounds__(256) void attn_fwd(const bf16* __restrict__ qg,
                                                const bf16* __restrict__ kg,
                                                const bf16* __restrict__ vtg,
                                                bf16* __restrict__ og) {
  __shared__ __align__(16) bf16 Sl[3][4096];
  __shared__ __align__(16) bf16 Pl[4][1024];  // stride 64, XOR-swizzled chunks

  const int tid = threadIdx.x;
  const int l = tid & 63, w = tid >> 6;
  const int lr = l & 15, lg = l >> 4;
  const int bh = blockIdx.x;          // head-major: 4 heads per XCD
  const int qt = 31 - blockIdx.y;     // largest work first
  const int q0 = qt * 64;
  const size_t hb = (size_t)bh * SDIM * HDIM;
  const bf16* Q  = qg + hb;
  const bf16* Kp = kg + hb;
  const bf16* Vp = vtg + hb;  // [64][SDIM]
  const int b = bh >> 4, h = bh & 15;
  bf16* Pw = &Pl[w][0];
  const int swz = lr & 7;

  const int mm0 = 2 * w, mm1 = 2 * w + 1;
  const int f0 = mm0 & 3, c0 = mm0 >> 2;
  const int f1 = mm1 & 3, c1 = mm1 >> 2;
  const int lo0 = mm0 * 512 + l * 8;   // lane's LDS offset for chunk mm0
  const int lo1 = mm1 * 512 + l * 8;

  bf16x8 qf[2];
#pragma unroll
  for (int c = 0; c < 2; ++c)
    qf[c] = *(const bf16x8*)(Q + (size_t)(q0 + w * 16 + lr) * HDIM + c * 32 + lg * 8);

  f32x4 o[4] = {};
  float m = -3e38f, lsum = 0.f;

  // per-lane source pointers, advanced by constant stride per tile
  const bf16* kN0 = Kp + (size_t)(f0 * 16 + lr) * HDIM + c0 * 32 + lg * 8;
  const bf16* kN1 = Kp + (size_t)(f1 * 16 + lr) * HDIM + c1 * 32 + lg * 8;
  const bf16* vN0 = Vp + (size_t)(f0 * 16 + lr) * SDIM + c0 * 32 + lg * 8;
  const bf16* vN1 = Vp + (size_t)(f1 * 16 + lr) * SDIM + c1 * 32 + lg * 8;

  // prologue: K0 -> slot0, V0 -> slot1
  ASYNC16(kN0, Sl[0] + lo0); kN0 += 64 * HDIM;
  ASYNC16(kN1, Sl[0] + lo1); kN1 += 64 * HDIM;
  ASYNC16(vN0, Sl[1] + lo0); vN0 += 64;
  ASYNC16(vN1, Sl[1] + lo1); vN1 += 64;
  __syncthreads();

  int ks = 0, vs = 1;
  for (int t = 0; t <= qt; ++t) {
    const int kn = 3 - ks - vs;
    // stage next K into the free slot (hidden under this tile's compute)
    if (t < qt) {
      ASYNC16(kN0, Sl[kn] + lo0); kN0 += 64 * HDIM;
      ASYNC16(kN1, Sl[kn] + lo1); kN1 += 64 * HDIM;
    }

    const bool diag = (t == qt);
    const int fLim = diag ? w : 3;

    // swapped QK^T: sc[f] col=q-row(lr), row=key(f*16+lg*4+r)
    f32x4 sc[4] = {};
    __builtin_amdgcn_s_setprio(1);
#pragma unroll
    for (int c = 0; c < 2; ++c)
#pragma unroll
      for (int f = 0; f < 4; ++f)
        if (f <= fLim) {
          bf16x8 kfr = *(const bf16x8*)(Sl[ks] + (c * 4 + f) * 512 + l * 8);
          sc[f] = MFMA16(kfr, qf[c], sc[f]);
        }
    __builtin_amdgcn_s_setprio(0);

    __syncthreads();  // all waves done reading K slot; K-next may land anytime
    // stage next V into the K slot just freed
    if (t < qt) {
      ASYNC16(vN0, Sl[ks] + lo0); vN0 += 64;
      ASYNC16(vN1, Sl[ks] + lo1); vN1 += 64;
    }

    if (diag) {
#pragma unroll
      for (int f = 0; f < 4; ++f)
#pragma unroll
        for (int r = 0; r < 4; ++r) {
          if (f > w)
            sc[f][r] = -3e38f;
          else if (f == w)
            sc[f][r] = (lg * 4 + r <= lr) ? sc[f][r] : -3e38f;
        }
    }

    // per-lane local max drives defer-max; cross-lane reduce only on trigger
    float mxl = -3e38f;
#pragma unroll
    for (int f = 0; f < 4; ++f)
#pragma unroll
      for (int r = 0; r < 4; ++r) mxl = fmaxf(mxl, sc[f][r]);

    if (!__all(mxl - m <= 8.f)) {
      float mx = fmaxf(mxl, __shfl_xor(mxl, 16));
      mx = fmaxf(mx, __shfl_xor(mx, 32));
      float mnew = fmaxf(m, mx);
      float corr = exp2f(m - mnew);
      m = mnew;
      lsum *= corr;
      float cb[4];
#pragma unroll
      for (int r = 0; r < 4; ++r) cb[r] = __shfl(corr, lg * 4 + r);
#pragma unroll
      for (int n = 0; n < 4; ++n)
#pragma unroll
        for (int r = 0; r < 4; ++r) o[n][r] *= cb[r];
    }

    // P = exp2(sc - m); packed b64 stores into swizzled chunks
    float rs = 0.f;
#pragma unroll
    for (int f = 0; f < 4; ++f) {
      float p0 = exp2f(sc[f][0] - m);
      float p1 = exp2f(sc[f][1] - m);
      float p2 = exp2f(sc[f][2] - m);
      float p3 = exp2f(sc[f][3] - m);
      rs += (p0 + p1) + (p2 + p3);
      bf16x4 pv = {(__bf16)p0, (__bf16)p1, (__bf16)p2, (__bf16)p3};
      const int ch = f * 2 + (lg >> 1);
      *(bf16x4*)(Pw + lr * 64 + ((ch ^ swz) << 3) + (lg & 1) * 4) = pv;
    }
    rs += __shfl_xor(rs, 16);
    rs += __shfl_xor(rs, 32);
    lsum += rs;

    // PV (skip fully-zero key chunks on the diagonal tile)
    const int cLim = diag ? (w >> 1) : 1;
    __builtin_amdgcn_s_setprio(1);
#pragma unroll
    for (int c = 0; c < 2; ++c)
      if (c <= cLim) {
        bf16x8 pf = *(const bf16x8*)(Pw + lr * 64 + (((c * 4 + lg) ^ swz) << 3));
#pragma unroll
        for (int n = 0; n < 4; ++n) {
          bf16x8 vfr = *(const bf16x8*)(Sl[vs] + (c * 4 + n) * 512 + l * 8);
          o[n] = MFMA16(pf, vfr, o[n]);
        }
      }
    __builtin_amdgcn_s_setprio(0);

    __syncthreads();  // V slot consumed by all; K-next & V-next arrived
    vs = ks;
    ks = kn;
  }

  // epilogue: broadcast lsum from softmax layout (per lr) to O layout (per lg*4+r)
  float lb[4];
#pragma unroll
  for (int r = 0; r < 4; ++r) lb[r] = __shfl(lsum, lg * 4 + r);
#pragma unroll
  for (int r = 0; r < 4; ++r) {
    float rl = 1.f / lb[r];
    int qr = q0 + 16 * w + lg * 4 + r;
#pragma unroll
    for (int n = 0; n < 4; ++n)
      og[((size_t)(b * SDIM + qr)) * DDIM + h * HDIM + n * 16 + lr] =
          (__bf16)(o[n][r] * rl);
  }
}

// ---------------------------------------------------------------- launch
extern "C" void kernel_launch(void* const* d_in, const int* in_sizes, int n_in,
                              void* d_out, int out_size, void* d_ws, size_t ws_size,
                              hipStream_t stream) {
  const float* x  = (const float*)d_in[0];
  const float* wq = (const float*)d_in[1];
  const float* wk = (const float*)d_in[2];
  const float* wv = (const float*)d_in[3];
  const float* wo = (const float*)d_in[4];

  char* ws = (char*)d_ws;
  const size_t MB = 1024 * 1024;
  bf16* xb   = (bf16*)(ws + 0);        // 8 MB (reused as vtb after QKV GEMM)
  bf16* wqb  = (bf16*)(ws + 8 * MB);   // wq,wk,wv,wo contiguous (2 MB each)
  bf16* wob  = (bf16*)(ws + 14 * MB);
  bf16* qb   = (bf16*)(ws + 16 * MB);  // Q [bh][s][64]
  bf16* kb   = (bf16*)(ws + 24 * MB);  // K [bh][s][64]
  bf16* vb   = (bf16*)(ws + 32 * MB);  // V [bh][s][64]
  bf16* ob   = (bf16*)(ws + 40 * MB);  // attention output [B][S][D]
  float* cosT = (float*)(ws + 48 * MB);
  float* sinT = (float*)(ws + 49 * MB);
  bf16* vtb  = xb;  // V transposed [bh][64][S], overwrites xb (free after QKV GEMM)

  const int NX = BDIM * SDIM * DDIM;  // 4194304
  const int NW = DDIM * DDIM;         // 1048576

  cvt_bf16<<<NX / 4 / 256, 256, 0, stream>>>(x, xb, NX / 4);
  Ptr4 wsrc{{wq, wk, wv, wo}};
  cvt_w<<<dim3(NW / 4 / 256, 4), 256, 0, stream>>>(wsrc, wqb);
  rope_table<<<(SDIM * 32) / 256, 256, 0, stream>>>(cosT, sinT);
  gemm_bt<0><<<dim3(8, 32, 3), 256, 0, stream>>>(xb, wqb, (void*)qb);
  fixup_qkv<<<dim3(SDIM / 32, 32), 256, 0, stream>>>(qb, kb, (const unsigned short*)vb,
                                                     (unsigned short*)vtb, cosT, sinT);
  attn_fwd<<<dim3(32, 32), 256, 0, stream>>>(qb, kb, vtb, ob);
  gemm_bt<1><<<dim3(8, 32, 1), 256, 0, stream>>>(ob, wob, d_out);
}

// Round 8
// 137.691 us; speedup vs baseline: 1.1160x; 1.0348x over previous
//
#include <hip/hip_runtime.h>
#include <hip/hip_bf16.h>
#include <cstdint>
#include <cstddef>

// Problem constants
#define BDIM 2
#define SDIM 2048
#define DDIM 1024
#define HN   16
#define HDIM 64

using bf16 = __bf16;
typedef __attribute__((ext_vector_type(8))) __bf16 bf16x8;
typedef __attribute__((ext_vector_type(4))) __bf16 bf16x4;
typedef __attribute__((ext_vector_type(8))) unsigned short ushort8;
typedef __attribute__((ext_vector_type(4))) float  f32x4;

#define MFMA16(a, b, c) __builtin_amdgcn_mfma_f32_16x16x32_bf16((a), (b), (c), 0, 0, 0)

#define ASYNC16(g, l)                                                          \
  __builtin_amdgcn_global_load_lds(                                            \
      (const __attribute__((address_space(1))) void*)(g),                      \
      (__attribute__((address_space(3))) void*)(l), 16, 0, 0)

// scale folded into Q at rope time: 1/sqrt(64) * log2(e)  (softmax in exp2 domain)
#define QSCALE 0.1803368801111204f

// ---------------------------------------------------------------- conversions
__global__ __launch_bounds__(256) void cvt_bf16(const float* __restrict__ src,
                                                bf16* __restrict__ dst, int n4) {
  int i = blockIdx.x * 256 + threadIdx.x;
  if (i < n4) {
    float4 v = ((const float4*)src)[i];
    bf16x4 o = {(__bf16)v.x, (__bf16)v.y, (__bf16)v.z, (__bf16)v.w};
    *(bf16x4*)(dst + (size_t)i * 4) = o;
  }
}

struct Ptr4 { const float* p[4]; };
// 4 weight matrices -> contiguous bf16 (wq,wk,wv,wo), grid.y = segment
__global__ __launch_bounds__(256) void cvt_w(Ptr4 srcs, bf16* __restrict__ dst) {
  const int seg = blockIdx.y;
  const float* src = srcs.p[seg];
  int i = blockIdx.x * 256 + threadIdx.x;  // < NW/4
  float4 v = ((const float4*)src)[i];
  bf16x4 o = {(__bf16)v.x, (__bf16)v.y, (__bf16)v.z, (__bf16)v.w};
  *(bf16x4*)(dst + (size_t)seg * (DDIM * DDIM) + (size_t)i * 4) = o;
}

// ---------------------------------------------------------------- rope table
__global__ __launch_bounds__(256) void rope_table(float* __restrict__ cosT,
                                                  float* __restrict__ sinT) {
  int i = blockIdx.x * 256 + threadIdx.x;  // SDIM*32 threads
  int s = i >> 5, j = i & 31;
  float inv = powf(10000.f, -(float)j * (1.f / 32.f));
  float a = (float)s * inv;
  float sn, c;
  sincosf(a, &sn, &c);
  cosT[s * 64 + j]      = c;
  cosT[s * 64 + j + 32] = c;
  sinT[s * 64 + j]      = sn;
  sinT[s * 64 + j + 32] = sn;
}

// ---------------------------------------------------------------- fused: rope(q,k) + transpose(v)
__global__ __launch_bounds__(256) void fixup_qkv(bf16* __restrict__ q,
                                                 bf16* __restrict__ k,
                                                 const unsigned short* __restrict__ v,
                                                 unsigned short* __restrict__ vt,
                                                 const float* __restrict__ cosT,
                                                 const float* __restrict__ sinT) {
  const int bh = blockIdx.y;
  const int s0 = blockIdx.x * 32;
  const int tid = threadIdx.x;

  // ---- rope on q and k: thread -> (s, 4-wide j group)
  {
    const int s = s0 + (tid >> 3);
    const int j0 = (tid & 7) * 4;
    const size_t base = ((size_t)bh * SDIM + s) * HDIM;
    const float4 c4 = *(const float4*)(cosT + s * 64 + j0);
    const float4 s4 = *(const float4*)(sinT + s * 64 + j0);
    const float cc[4] = {c4.x, c4.y, c4.z, c4.w};
    const float ss[4] = {s4.x, s4.y, s4.z, s4.w};

    bf16x4 qlo = *(bf16x4*)(q + base + j0);
    bf16x4 qhi = *(bf16x4*)(q + base + j0 + 32);
    bf16x4 klo = *(bf16x4*)(k + base + j0);
    bf16x4 khi = *(bf16x4*)(k + base + j0 + 32);
    bf16x4 rql, rqh, rkl, rkh;
#pragma unroll
    for (int e = 0; e < 4; ++e) {
      float a = (float)qlo[e], b = (float)qhi[e];
      rql[e] = (__bf16)((a * cc[e] - b * ss[e]) * QSCALE);
      rqh[e] = (__bf16)((b * cc[e] + a * ss[e]) * QSCALE);
      a = (float)klo[e]; b = (float)khi[e];
      rkl[e] = (__bf16)(a * cc[e] - b * ss[e]);
      rkh[e] = (__bf16)(b * cc[e] + a * ss[e]);
    }
    *(bf16x4*)(q + base + j0)      = rql;
    *(bf16x4*)(q + base + j0 + 32) = rqh;
    *(bf16x4*)(k + base + j0)      = rkl;
    *(bf16x4*)(k + base + j0 + 32) = rkh;
  }

  // ---- v transpose: [bh][s][64] -> [bh][64][s]
  {
    const int w = tid >> 6, d = tid & 63;
    const int sb = s0 + w * 8;
    const unsigned short* src = v + ((size_t)bh * SDIM + sb) * HDIM + d;
    ushort8 o;
#pragma unroll
    for (int j = 0; j < 8; ++j) o[j] = src[(size_t)j * HDIM];
    *(ushort8*)(vt + ((size_t)bh * HDIM + d) * SDIM + sb) = o;
  }
}

// ---------------------------------------------------------------- GEMM  C = A * B^T
template <int MODE>
__global__ __launch_bounds__(256) void gemm_bt(const bf16* __restrict__ A,
                                               const bf16* __restrict__ B0,
                                               void* __restrict__ C0) {
  constexpr int K = 1024;
  __shared__ __align__(16) bf16 As[128 * 64];
  __shared__ __align__(16) bf16 Bs[128 * 64];
  const int tid = threadIdx.x;
  const int l = tid & 63, w = tid >> 6;
  const int wr = w >> 1, wc = w & 1;
  const int lr = l & 15, lg = l >> 4;
  const int bm = blockIdx.y * 128;
  const int bn = blockIdx.x * 128;
  const bf16* Bw = B0 + (size_t)blockIdx.z * (1024 * 1024);

  f32x4 acc[4][4] = {};

  for (int k0 = 0; k0 < K; k0 += 64) {
    __syncthreads();
#pragma unroll
    for (int i = 0; i < 4; ++i) {
      int idx = i * 2048 + tid * 8;
      int row = idx >> 6, col = idx & 63;
      ASYNC16(A + (size_t)(bm + row) * K + (k0 + col), As + idx);
      ASYNC16(Bw + (size_t)(bn + row) * K + (k0 + col), Bs + idx);
    }
    __syncthreads();
#pragma unroll
    for (int c = 0; c < 2; ++c) {
      bf16x8 af[4], bfr[4];
#pragma unroll
      for (int m = 0; m < 4; ++m)
        af[m] = *(const bf16x8*)(As + (wr * 64 + m * 16 + lr) * 64 + c * 32 + lg * 8);
#pragma unroll
      for (int n = 0; n < 4; ++n)
        bfr[n] = *(const bf16x8*)(Bs + (wc * 64 + n * 16 + lr) * 64 + c * 32 + lg * 8);
      __builtin_amdgcn_s_setprio(1);
#pragma unroll
      for (int m = 0; m < 4; ++m)
#pragma unroll
        for (int n = 0; n < 4; ++n)
          acc[m][n] = MFMA16(af[m], bfr[n], acc[m][n]);
      __builtin_amdgcn_s_setprio(0);
    }
  }

#pragma unroll
  for (int m = 0; m < 4; ++m) {
#pragma unroll
    for (int n = 0; n < 4; ++n) {
#pragma unroll
      for (int r = 0; r < 4; ++r) {
        int row = bm + wr * 64 + m * 16 + lg * 4 + r;
        int col = bn + wc * 64 + n * 16 + lr;
        float v = acc[m][n][r];
        if constexpr (MODE == 0) {
          bf16* C = (bf16*)C0 + (size_t)blockIdx.z * ((size_t)BDIM * SDIM * DDIM);
          size_t off = (((size_t)(row >> 11) * HN + (col >> 6)) * SDIM + (row & (SDIM - 1))) * HDIM + (col & 63);
          C[off] = (__bf16)v;
        } else {
          ((float*)C0)[(size_t)row * DDIM + col] = v;
        }
      }
    }
  }
}

// ---------------------------------------------------------------- flash attention (causal, swapped-QK^T, split-KV)
// 8 waves / block. Wave-group g (waves 4g..4g+3) processes KV tiles t ≡ g (mod 2)
// with its own 3-slot LDS rotation; independent online softmax per group;
// in-block merge at the end (group1 publishes m/l/o via LDS, group0 combines).
// Longest block: 16 serial steps (was 32) -> critical path halved.
__global__ __launch_bounds__(512) void attn_fwd(const bf16* __restrict__ qg,
                                                const bf16* __restrict__ kg,
                                                const bf16* __restrict__ vtg,
                                                bf16* __restrict__ og) {
  __shared__ __align__(16) bf16 Sl[2][3][4096];  // per-group rotating K/V slots (48 KB)
  __shared__ __align__(16) bf16 Pl[8][1024];     // per-wave P, XOR-chunk-swizzled (16 KB)

  const int tid = threadIdx.x;
  const int l = tid & 63, w = tid >> 6;   // w: 0..7
  const int g = w >> 2, wg = w & 3;       // group, wave-in-group
  const int lr = l & 15, lg = l >> 4;
  const int bh = blockIdx.x;              // head-major: 4 heads per XCD
  const int qt = 31 - blockIdx.y;         // largest work first
  const int q0 = qt * 64;
  const size_t hb = (size_t)bh * SDIM * HDIM;
  const bf16* Q  = qg + hb;
  const bf16* Kp = kg + hb;
  const bf16* Vp = vtg + hb;  // [64][SDIM]
  const int b = bh >> 4, h = bh & 15;
  bf16* Pw = &Pl[w][0];
  const int swz = lr & 7;

  const int mm0 = 2 * wg, mm1 = 2 * wg + 1;
  const int f0 = mm0 & 3, c0 = mm0 >> 2;
  const int f1 = mm1 & 3, c1 = mm1 >> 2;
  const int lo0 = mm0 * 512 + l * 8;
  const int lo1 = mm1 * 512 + l * 8;
  bf16* const SlG = &Sl[g][0][0];

  bf16x8 qf[2];
#pragma unroll
  for (int c = 0; c < 2; ++c)
    qf[c] = *(const bf16x8*)(Q + (size_t)(q0 + wg * 16 + lr) * HDIM + c * 32 + lg * 8);

  f32x4 o[4] = {};
  float m = -3e38f, lsum = 0.f;

  // group g's tiles: t = g, g+2, ... <= qt
  const int ng   = (qt >= g) ? ((qt - g) >> 1) + 1 : 0;
  const int smax = (qt >> 1) + 1;

  // per-lane source pointers (start at tile g; stride 2 tiles = 128 rows/keys)
  const bf16* kN0 = Kp + (size_t)(f0 * 16 + lr) * HDIM + c0 * 32 + lg * 8 + (size_t)g * 64 * HDIM;
  const bf16* kN1 = Kp + (size_t)(f1 * 16 + lr) * HDIM + c1 * 32 + lg * 8 + (size_t)g * 64 * HDIM;
  const bf16* vN0 = Vp + (size_t)(f0 * 16 + lr) * SDIM + c0 * 32 + lg * 8 + g * 64;
  const bf16* vN1 = Vp + (size_t)(f1 * 16 + lr) * SDIM + c1 * 32 + lg * 8 + g * 64;

  // prologue: K(tile g) -> slot0, V(tile g) -> slot1
  if (ng > 0) {
    ASYNC16(kN0, SlG + 0 * 4096 + lo0); kN0 += 128 * HDIM;
    ASYNC16(kN1, SlG + 0 * 4096 + lo1); kN1 += 128 * HDIM;
    ASYNC16(vN0, SlG + 1 * 4096 + lo0); vN0 += 128;
    ASYNC16(vN1, SlG + 1 * 4096 + lo1); vN1 += 128;
  }
  __syncthreads();

  int ks = 0, vs = 1;
  for (int s = 0; s < smax; ++s) {
    const int t = 2 * s + g;
    const bool act = (s < ng);
    const int kn = 3 - ks - vs;
    const bool hasNext = act && (s + 1 < ng);

    if (hasNext) {  // stage next K into the free slot
      ASYNC16(kN0, SlG + kn * 4096 + lo0); kN0 += 128 * HDIM;
      ASYNC16(kN1, SlG + kn * 4096 + lo1); kN1 += 128 * HDIM;
    }

    const bool diag = (t == qt);
    const int fLim = diag ? wg : 3;

    f32x4 sc[4] = {};
    if (act) {
      __builtin_amdgcn_s_setprio(1);
#pragma unroll
      for (int c = 0; c < 2; ++c)
#pragma unroll
        for (int f = 0; f < 4; ++f)
          if (f <= fLim) {
            bf16x8 kfr = *(const bf16x8*)(SlG + ks * 4096 + (c * 4 + f) * 512 + l * 8);
            sc[f] = MFMA16(kfr, qf[c], sc[f]);
          }
      __builtin_amdgcn_s_setprio(0);
    }

    __syncthreads();  // group done reading its K slot
    if (hasNext) {    // stage next V into the K slot just freed
      ASYNC16(vN0, SlG + ks * 4096 + lo0); vN0 += 128;
      ASYNC16(vN1, SlG + ks * 4096 + lo1); vN1 += 128;
    }

    if (act) {
      if (diag) {
#pragma unroll
        for (int f = 0; f < 4; ++f)
#pragma unroll
          for (int r = 0; r < 4; ++r) {
            if (f > wg)
              sc[f][r] = -3e38f;
            else if (f == wg)
              sc[f][r] = (lg * 4 + r <= lr) ? sc[f][r] : -3e38f;
          }
      }

      float mxl = -3e38f;
#pragma unroll
      for (int f = 0; f < 4; ++f)
#pragma unroll
        for (int r = 0; r < 4; ++r) mxl = fmaxf(mxl, sc[f][r]);

      if (!__all(mxl - m <= 8.f)) {
        float mx = fmaxf(mxl, __shfl_xor(mxl, 16));
        mx = fmaxf(mx, __shfl_xor(mx, 32));
        float mnew = fmaxf(m, mx);
        float corr = exp2f(m - mnew);
        m = mnew;
        lsum *= corr;
        float cb[4];
#pragma unroll
        for (int r = 0; r < 4; ++r) cb[r] = __shfl(corr, lg * 4 + r);
#pragma unroll
        for (int n = 0; n < 4; ++n)
#pragma unroll
          for (int r = 0; r < 4; ++r) o[n][r] *= cb[r];
      }

      float rs = 0.f;
#pragma unroll
      for (int f = 0; f < 4; ++f) {
        float p0 = exp2f(sc[f][0] - m);
        float p1 = exp2f(sc[f][1] - m);
        float p2 = exp2f(sc[f][2] - m);
        float p3 = exp2f(sc[f][3] - m);
        rs += (p0 + p1) + (p2 + p3);
        bf16x4 pv = {(__bf16)p0, (__bf16)p1, (__bf16)p2, (__bf16)p3};
        const int ch = f * 2 + (lg >> 1);
        *(bf16x4*)(Pw + lr * 64 + ((ch ^ swz) << 3) + (lg & 1) * 4) = pv;
      }
      rs += __shfl_xor(rs, 16);
      rs += __shfl_xor(rs, 32);
      lsum += rs;

      const int cLim = diag ? (wg >> 1) : 1;
      __builtin_amdgcn_s_setprio(1);
#pragma unroll
      for (int c = 0; c < 2; ++c)
        if (c <= cLim) {
          bf16x8 pf = *(const bf16x8*)(Pw + lr * 64 + (((c * 4 + lg) ^ swz) << 3));
#pragma unroll
          for (int n = 0; n < 4; ++n) {
            bf16x8 vfr = *(const bf16x8*)(SlG + vs * 4096 + (c * 4 + n) * 512 + l * 8);
            o[n] = MFMA16(pf, vfr, o[n]);
          }
        }
      __builtin_amdgcn_s_setprio(0);
    }

    __syncthreads();  // V slot consumed; next K/V landed
    vs = ks;
    ks = kn;
  }

  // ---- in-block merge of the two groups' partials (overlay on staging LDS)
  float* Osh = (float*)&Sl[0][0][0];  // [4][4][4][64] = 16 KB
  float* Msh = Osh + 4096;            // [4][64]
  float* Lsh = Msh + 256;             // [4][64]

  if (g == 1) {
    Msh[wg * 64 + l] = m;
    Lsh[wg * 64 + l] = lsum;
#pragma unroll
    for (int n = 0; n < 4; ++n)
#pragma unroll
      for (int r = 0; r < 4; ++r)
        Osh[((wg * 4 + n) * 4 + r) * 64 + l] = o[n][r];
  }
  __syncthreads();

  if (g == 0) {
    float m1 = Msh[wg * 64 + l], l1 = Lsh[wg * 64 + l];
    float mt = fmaxf(m, m1);
    float a0 = exp2f(m - mt), a1 = exp2f(m1 - mt);
    float lt = lsum * a0 + l1 * a1;
    float a0b[4], a1b[4], ltb[4];
#pragma unroll
    for (int r = 0; r < 4; ++r) {
      a0b[r] = __shfl(a0, lg * 4 + r);
      a1b[r] = __shfl(a1, lg * 4 + r);
      ltb[r] = __shfl(lt, lg * 4 + r);
    }
#pragma unroll
    for (int r = 0; r < 4; ++r) {
      float rl = 1.f / ltb[r];
      int qr = q0 + 16 * wg + lg * 4 + r;
#pragma unroll
      for (int n = 0; n < 4; ++n) {
        float o1 = Osh[((wg * 4 + n) * 4 + r) * 64 + l];
        og[((size_t)(b * SDIM + qr)) * DDIM + h * HDIM + n * 16 + lr] =
            (__bf16)((o[n][r] * a0b[r] + o1 * a1b[r]) * rl);
      }
    }
  }
}

// ---------------------------------------------------------------- launch
extern "C" void kernel_launch(void* const* d_in, const int* in_sizes, int n_in,
                              void* d_out, int out_size, void* d_ws, size_t ws_size,
                              hipStream_t stream) {
  const float* x  = (const float*)d_in[0];
  const float* wq = (const float*)d_in[1];
  const float* wk = (const float*)d_in[2];
  const float* wv = (const float*)d_in[3];
  const float* wo = (const float*)d_in[4];

  char* ws = (char*)d_ws;
  const size_t MB = 1024 * 1024;
  bf16* xb   = (bf16*)(ws + 0);        // 8 MB (reused as vtb after QKV GEMM)
  bf16* wqb  = (bf16*)(ws + 8 * MB);   // wq,wk,wv,wo contiguous (2 MB each)
  bf16* wob  = (bf16*)(ws + 14 * MB);
  bf16* qb   = (bf16*)(ws + 16 * MB);  // Q [bh][s][64]
  bf16* kb   = (bf16*)(ws + 24 * MB);  // K [bh][s][64]
  bf16* vb   = (bf16*)(ws + 32 * MB);  // V [bh][s][64]
  bf16* ob   = (bf16*)(ws + 40 * MB);  // attention output [B][S][D]
  float* cosT = (float*)(ws + 48 * MB);
  float* sinT = (float*)(ws + 49 * MB);
  bf16* vtb  = xb;  // V transposed [bh][64][S], overwrites xb (free after QKV GEMM)

  const int NX = BDIM * SDIM * DDIM;  // 4194304
  const int NW = DDIM * DDIM;         // 1048576

  cvt_bf16<<<NX / 4 / 256, 256, 0, stream>>>(x, xb, NX / 4);
  Ptr4 wsrc{{wq, wk, wv, wo}};
  cvt_w<<<dim3(NW / 4 / 256, 4), 256, 0, stream>>>(wsrc, wqb);
  rope_table<<<(SDIM * 32) / 256, 256, 0, stream>>>(cosT, sinT);
  gemm_bt<0><<<dim3(8, 32, 3), 256, 0, stream>>>(xb, wqb, (void*)qb);
  fixup_qkv<<<dim3(SDIM / 32, 32), 256, 0, stream>>>(qb, kb, (const unsigned short*)vb,
                                                     (unsigned short*)vtb, cosT, sinT);
  attn_fwd<<<dim3(32, 32), 512, 0, stream>>>(qb, kb, vtb, ob);
  gemm_bt<1><<<dim3(8, 32, 1), 256, 0, stream>>>(ob, wob, d_out);
}

// Round 9
// 135.972 us; speedup vs baseline: 1.1301x; 1.0126x over previous
//
#include <hip/hip_runtime.h>
#include <hip/hip_bf16.h>
#include <cstdint>
#include <cstddef>

// Problem constants
#define BDIM 2
#define SDIM 2048
#define DDIM 1024
#define HN   16
#define HDIM 64

using bf16 = __bf16;
typedef __attribute__((ext_vector_type(8))) __bf16 bf16x8;
typedef __attribute__((ext_vector_type(4))) __bf16 bf16x4;
typedef __attribute__((ext_vector_type(8))) unsigned short ushort8;
typedef __attribute__((ext_vector_type(4))) float  f32x4;

#define MFMA16(a, b, c) __builtin_amdgcn_mfma_f32_16x16x32_bf16((a), (b), (c), 0, 0, 0)

#define ASYNC16(g, l)                                                          \
  __builtin_amdgcn_global_load_lds(                                            \
      (const __attribute__((address_space(1))) void*)(g),                      \
      (__attribute__((address_space(3))) void*)(l), 16, 0, 0)

// scale folded into Q at rope time: 1/sqrt(64) * log2(e)  (softmax in exp2 domain)
#define QSCALE 0.1803368801111204f

// ---------------------------------------------------------------- conversions
__global__ __launch_bounds__(256) void cvt_bf16(const float* __restrict__ src,
                                                bf16* __restrict__ dst, int n4) {
  int i = blockIdx.x * 256 + threadIdx.x;
  if (i < n4) {
    float4 v = ((const float4*)src)[i];
    bf16x4 o = {(__bf16)v.x, (__bf16)v.y, (__bf16)v.z, (__bf16)v.w};
    *(bf16x4*)(dst + (size_t)i * 4) = o;
  }
}

struct Ptr4 { const float* p[4]; };
// 4 weight matrices -> contiguous bf16 (wq,wk,wv,wo), grid.y = segment
__global__ __launch_bounds__(256) void cvt_w(Ptr4 srcs, bf16* __restrict__ dst) {
  const int seg = blockIdx.y;
  const float* src = srcs.p[seg];
  int i = blockIdx.x * 256 + threadIdx.x;  // < NW/4
  float4 v = ((const float4*)src)[i];
  bf16x4 o = {(__bf16)v.x, (__bf16)v.y, (__bf16)v.z, (__bf16)v.w};
  *(bf16x4*)(dst + (size_t)seg * (DDIM * DDIM) + (size_t)i * 4) = o;
}

// ---------------------------------------------------------------- rope table
__global__ __launch_bounds__(256) void rope_table(float* __restrict__ cosT,
                                                  float* __restrict__ sinT) {
  int i = blockIdx.x * 256 + threadIdx.x;  // SDIM*32 threads
  int s = i >> 5, j = i & 31;
  float inv = powf(10000.f, -(float)j * (1.f / 32.f));
  float a = (float)s * inv;
  float sn, c;
  sincosf(a, &sn, &c);
  cosT[s * 64 + j]      = c;
  cosT[s * 64 + j + 32] = c;
  sinT[s * 64 + j]      = sn;
  sinT[s * 64 + j + 32] = sn;
}

// ---------------------------------------------------------------- fused: rope(q,k) + transpose(v)
__global__ __launch_bounds__(256) void fixup_qkv(bf16* __restrict__ q,
                                                 bf16* __restrict__ k,
                                                 const unsigned short* __restrict__ v,
                                                 unsigned short* __restrict__ vt,
                                                 const float* __restrict__ cosT,
                                                 const float* __restrict__ sinT) {
  const int bh = blockIdx.y;
  const int s0 = blockIdx.x * 32;
  const int tid = threadIdx.x;

  // ---- rope on q and k: thread -> (s, 4-wide j group)
  {
    const int s = s0 + (tid >> 3);
    const int j0 = (tid & 7) * 4;
    const size_t base = ((size_t)bh * SDIM + s) * HDIM;
    const float4 c4 = *(const float4*)(cosT + s * 64 + j0);
    const float4 s4 = *(const float4*)(sinT + s * 64 + j0);
    const float cc[4] = {c4.x, c4.y, c4.z, c4.w};
    const float ss[4] = {s4.x, s4.y, s4.z, s4.w};

    bf16x4 qlo = *(bf16x4*)(q + base + j0);
    bf16x4 qhi = *(bf16x4*)(q + base + j0 + 32);
    bf16x4 klo = *(bf16x4*)(k + base + j0);
    bf16x4 khi = *(bf16x4*)(k + base + j0 + 32);
    bf16x4 rql, rqh, rkl, rkh;
#pragma unroll
    for (int e = 0; e < 4; ++e) {
      float a = (float)qlo[e], b = (float)qhi[e];
      rql[e] = (__bf16)((a * cc[e] - b * ss[e]) * QSCALE);
      rqh[e] = (__bf16)((b * cc[e] + a * ss[e]) * QSCALE);
      a = (float)klo[e]; b = (float)khi[e];
      rkl[e] = (__bf16)(a * cc[e] - b * ss[e]);
      rkh[e] = (__bf16)(b * cc[e] + a * ss[e]);
    }
    *(bf16x4*)(q + base + j0)      = rql;
    *(bf16x4*)(q + base + j0 + 32) = rqh;
    *(bf16x4*)(k + base + j0)      = rkl;
    *(bf16x4*)(k + base + j0 + 32) = rkh;
  }

  // ---- v transpose: [bh][s][64] -> [bh][64][s]
  {
    const int w = tid >> 6, d = tid & 63;
    const int sb = s0 + w * 8;
    const unsigned short* src = v + ((size_t)bh * SDIM + sb) * HDIM + d;
    ushort8 o;
#pragma unroll
    for (int j = 0; j < 8; ++j) o[j] = src[(size_t)j * HDIM];
    *(ushort8*)(vt + ((size_t)bh * HDIM + d) * SDIM + sb) = o;
  }
}

// ---------------------------------------------------------------- GEMM  C = A * B^T
template <int MODE>
__global__ __launch_bounds__(256) void gemm_bt(const bf16* __restrict__ A,
                                               const bf16* __restrict__ B0,
                                               void* __restrict__ C0) {
  constexpr int K = 1024;
  __shared__ __align__(16) bf16 As[128 * 64];
  __shared__ __align__(16) bf16 Bs[128 * 64];
  const int tid = threadIdx.x;
  const int l = tid & 63, w = tid >> 6;
  const int wr = w >> 1, wc = w & 1;
  const int lr = l & 15, lg = l >> 4;
  const int bm = blockIdx.y * 128;
  const int bn = blockIdx.x * 128;
  const bf16* Bw = B0 + (size_t)blockIdx.z * (1024 * 1024);

  f32x4 acc[4][4] = {};

  for (int k0 = 0; k0 < K; k0 += 64) {
    __syncthreads();
#pragma unroll
    for (int i = 0; i < 4; ++i) {
      int idx = i * 2048 + tid * 8;
      int row = idx >> 6, col = idx & 63;
      ASYNC16(A + (size_t)(bm + row) * K + (k0 + col), As + idx);
      ASYNC16(Bw + (size_t)(bn + row) * K + (k0 + col), Bs + idx);
    }
    __syncthreads();
#pragma unroll
    for (int c = 0; c < 2; ++c) {
      bf16x8 af[4], bfr[4];
#pragma unroll
      for (int m = 0; m < 4; ++m)
        af[m] = *(const bf16x8*)(As + (wr * 64 + m * 16 + lr) * 64 + c * 32 + lg * 8);
#pragma unroll
      for (int n = 0; n < 4; ++n)
        bfr[n] = *(const bf16x8*)(Bs + (wc * 64 + n * 16 + lr) * 64 + c * 32 + lg * 8);
      __builtin_amdgcn_s_setprio(1);
#pragma unroll
      for (int m = 0; m < 4; ++m)
#pragma unroll
        for (int n = 0; n < 4; ++n)
          acc[m][n] = MFMA16(af[m], bfr[n], acc[m][n]);
      __builtin_amdgcn_s_setprio(0);
    }
  }

#pragma unroll
  for (int m = 0; m < 4; ++m) {
#pragma unroll
    for (int n = 0; n < 4; ++n) {
#pragma unroll
      for (int r = 0; r < 4; ++r) {
        int row = bm + wr * 64 + m * 16 + lg * 4 + r;
        int col = bn + wc * 64 + n * 16 + lr;
        float v = acc[m][n][r];
        if constexpr (MODE == 0) {
          bf16* C = (bf16*)C0 + (size_t)blockIdx.z * ((size_t)BDIM * SDIM * DDIM);
          size_t off = (((size_t)(row >> 11) * HN + (col >> 6)) * SDIM + (row & (SDIM - 1))) * HDIM + (col & 63);
          C[off] = (__bf16)v;
        } else {
          ((float*)C0)[(size_t)row * DDIM + col] = v;
        }
      }
    }
  }
}

// ---------------------------------------------------------------- flash attention (causal, swapped-QK^T, split-KV)
// 8 waves / block. Wave-group g processes KV tiles t ≡ g (mod 2) with its own
// 3-slot LDS rotation; independent online softmax per group; in-block merge.
// Mid-tile barrier is a RAW s_barrier (no vmcnt drain): K-next loads issued at
// loop top stay in flight across it and drain only at the end-of-step
// __syncthreads, hidden under QK^T+softmax+PV. lsum kept per-lane (no per-tile
// shuffles); reduced once at the end.
__global__ __launch_bounds__(512) void attn_fwd(const bf16* __restrict__ qg,
                                                const bf16* __restrict__ kg,
                                                const bf16* __restrict__ vtg,
                                                bf16* __restrict__ og) {
  __shared__ __align__(16) bf16 Sl[2][3][4096];  // per-group rotating K/V slots (48 KB)
  __shared__ __align__(16) bf16 Pl[8][1024];     // per-wave P, XOR-chunk-swizzled (16 KB)

  const int tid = threadIdx.x;
  const int l = tid & 63, w = tid >> 6;   // w: 0..7
  const int g = w >> 2, wg = w & 3;       // group, wave-in-group
  const int lr = l & 15, lg = l >> 4;
  const int bh = blockIdx.x;              // head-major: 4 heads per XCD
  const int qt = 31 - blockIdx.y;         // largest work first
  const int q0 = qt * 64;
  const size_t hb = (size_t)bh * SDIM * HDIM;
  const bf16* Q  = qg + hb;
  const bf16* Kp = kg + hb;
  const bf16* Vp = vtg + hb;  // [64][SDIM]
  const int b = bh >> 4, h = bh & 15;
  bf16* Pw = &Pl[w][0];
  const int swz = lr & 7;

  const int mm0 = 2 * wg, mm1 = 2 * wg + 1;
  const int f0 = mm0 & 3, c0 = mm0 >> 2;
  const int f1 = mm1 & 3, c1 = mm1 >> 2;
  const int lo0 = mm0 * 512 + l * 8;
  const int lo1 = mm1 * 512 + l * 8;
  bf16* const SlG = &Sl[g][0][0];

  bf16x8 qf[2];
#pragma unroll
  for (int c = 0; c < 2; ++c)
    qf[c] = *(const bf16x8*)(Q + (size_t)(q0 + wg * 16 + lr) * HDIM + c * 32 + lg * 8);

  f32x4 o[4] = {};
  float m = -3e38f, lsum = 0.f;  // lsum is a PER-LANE partial

  // group g's tiles: t = g, g+2, ... <= qt
  const int ng   = (qt >= g) ? ((qt - g) >> 1) + 1 : 0;
  const int smax = (qt >> 1) + 1;

  // per-lane source pointers (start at tile g; stride 2 tiles = 128 rows/keys)
  const bf16* kN0 = Kp + (size_t)(f0 * 16 + lr) * HDIM + c0 * 32 + lg * 8 + (size_t)g * 64 * HDIM;
  const bf16* kN1 = Kp + (size_t)(f1 * 16 + lr) * HDIM + c1 * 32 + lg * 8 + (size_t)g * 64 * HDIM;
  const bf16* vN0 = Vp + (size_t)(f0 * 16 + lr) * SDIM + c0 * 32 + lg * 8 + g * 64;
  const bf16* vN1 = Vp + (size_t)(f1 * 16 + lr) * SDIM + c1 * 32 + lg * 8 + g * 64;

  // prologue: K(tile g) -> slot0, V(tile g) -> slot1
  if (ng > 0) {
    ASYNC16(kN0, SlG + 0 * 4096 + lo0); kN0 += 128 * HDIM;
    ASYNC16(kN1, SlG + 0 * 4096 + lo1); kN1 += 128 * HDIM;
    ASYNC16(vN0, SlG + 1 * 4096 + lo0); vN0 += 128;
    ASYNC16(vN1, SlG + 1 * 4096 + lo1); vN1 += 128;
  }
  __syncthreads();

  int ks = 0, vs = 1;
  for (int s = 0; s < smax; ++s) {
    const int t = 2 * s + g;
    const bool act = (s < ng);
    const int kn = 3 - ks - vs;
    const bool hasNext = act && (s + 1 < ng);

    if (hasNext) {  // stage next K into the free slot
      ASYNC16(kN0, SlG + kn * 4096 + lo0); kN0 += 128 * HDIM;
      ASYNC16(kN1, SlG + kn * 4096 + lo1); kN1 += 128 * HDIM;
    }

    const bool diag = (t == qt);
    const int fLim = diag ? wg : 3;

    f32x4 sc[4] = {};
    if (act) {
      __builtin_amdgcn_s_setprio(1);
#pragma unroll
      for (int c = 0; c < 2; ++c)
#pragma unroll
        for (int f = 0; f < 4; ++f)
          if (f <= fLim) {
            bf16x8 kfr = *(const bf16x8*)(SlG + ks * 4096 + (c * 4 + f) * 512 + l * 8);
            sc[f] = MFMA16(kfr, qf[c], sc[f]);
          }
      __builtin_amdgcn_s_setprio(0);
    }

    // RAW barrier: all waves' K-slot ds_reads retired (each wave's MFMAs
    // consumed them); K-next global_load_lds stays IN FLIGHT across it.
    __builtin_amdgcn_s_barrier();
    __builtin_amdgcn_sched_barrier(0);

    if (hasNext) {    // stage next V into the K slot just freed
      ASYNC16(vN0, SlG + ks * 4096 + lo0); vN0 += 128;
      ASYNC16(vN1, SlG + ks * 4096 + lo1); vN1 += 128;
    }

    if (act) {
      if (diag) {
#pragma unroll
        for (int f = 0; f < 4; ++f)
#pragma unroll
          for (int r = 0; r < 4; ++r) {
            if (f > wg)
              sc[f][r] = -3e38f;
            else if (f == wg)
              sc[f][r] = (lg * 4 + r <= lr) ? sc[f][r] : -3e38f;
          }
      }

      float mxl = -3e38f;
#pragma unroll
      for (int f = 0; f < 4; ++f)
#pragma unroll
        for (int r = 0; r < 4; ++r) mxl = fmaxf(mxl, sc[f][r]);

      if (!__all(mxl - m <= 8.f)) {
        float mx = fmaxf(mxl, __shfl_xor(mxl, 16));
        mx = fmaxf(mx, __shfl_xor(mx, 32));
        float mnew = fmaxf(m, mx);
        float corr = exp2f(m - mnew);
        m = mnew;
        lsum *= corr;  // per-lane partial, row-uniform corr
        float cb[4];
#pragma unroll
        for (int r = 0; r < 4; ++r) cb[r] = __shfl(corr, lg * 4 + r);
#pragma unroll
        for (int n = 0; n < 4; ++n)
#pragma unroll
          for (int r = 0; r < 4; ++r) o[n][r] *= cb[r];
      }

      float rs = 0.f;
#pragma unroll
      for (int f = 0; f < 4; ++f) {
        float p0 = exp2f(sc[f][0] - m);
        float p1 = exp2f(sc[f][1] - m);
        float p2 = exp2f(sc[f][2] - m);
        float p3 = exp2f(sc[f][3] - m);
        rs += (p0 + p1) + (p2 + p3);
        bf16x4 pv = {(__bf16)p0, (__bf16)p1, (__bf16)p2, (__bf16)p3};
        const int ch = f * 2 + (lg >> 1);
        *(bf16x4*)(Pw + lr * 64 + ((ch ^ swz) << 3) + (lg & 1) * 4) = pv;
      }
      lsum += rs;  // no cross-lane reduce here (deferred to epilogue)

      const int cLim = diag ? (wg >> 1) : 1;
      __builtin_amdgcn_s_setprio(1);
#pragma unroll
      for (int c = 0; c < 2; ++c)
        if (c <= cLim) {
          bf16x8 pf = *(const bf16x8*)(Pw + lr * 64 + (((c * 4 + lg) ^ swz) << 3));
#pragma unroll
          for (int n = 0; n < 4; ++n) {
            bf16x8 vfr = *(const bf16x8*)(SlG + vs * 4096 + (c * 4 + n) * 512 + l * 8);
            o[n] = MFMA16(pf, vfr, o[n]);
          }
        }
      __builtin_amdgcn_s_setprio(0);
    }

    __syncthreads();  // drains this wave's K-next/V-next (hidden under compute)
    vs = ks;
    ks = kn;
  }

  // ---- in-block merge of the two groups' partials (overlay on staging LDS)
  float* Osh = (float*)&Sl[0][0][0];  // [4][4][4][64] = 16 KB
  float* Msh = Osh + 4096;            // [4][64]
  float* Lsh = Msh + 256;             // [4][64]

  if (g == 1) {
    Msh[wg * 64 + l] = m;
    Lsh[wg * 64 + l] = lsum;
#pragma unroll
    for (int n = 0; n < 4; ++n)
#pragma unroll
      for (int r = 0; r < 4; ++r)
        Osh[((wg * 4 + n) * 4 + r) * 64 + l] = o[n][r];
  }
  __syncthreads();

  if (g == 0) {
    float m1 = Msh[wg * 64 + l], l1 = Lsh[wg * 64 + l];
    float mt = fmaxf(m, m1);
    float a0 = exp2f(m - mt), a1 = exp2f(m1 - mt);
    float lt = lsum * a0 + l1 * a1;      // per-lane partial combine
    lt += __shfl_xor(lt, 16);            // deferred row reduce
    lt += __shfl_xor(lt, 32);
    float a0b[4], a1b[4], ltb[4];
#pragma unroll
    for (int r = 0; r < 4; ++r) {
      a0b[r] = __shfl(a0, lg * 4 + r);
      a1b[r] = __shfl(a1, lg * 4 + r);
      ltb[r] = __shfl(lt, lg * 4 + r);
    }
#pragma unroll
    for (int r = 0; r < 4; ++r) {
      float rl = 1.f / ltb[r];
      int qr = q0 + 16 * wg + lg * 4 + r;
#pragma unroll
      for (int n = 0; n < 4; ++n) {
        float o1 = Osh[((wg * 4 + n) * 4 + r) * 64 + l];
        og[((size_t)(b * SDIM + qr)) * DDIM + h * HDIM + n * 16 + lr] =
            (__bf16)((o[n][r] * a0b[r] + o1 * a1b[r]) * rl);
      }
    }
  }
}

// ---------------------------------------------------------------- launch
extern "C" void kernel_launch(void* const* d_in, const int* in_sizes, int n_in,
                              void* d_out, int out_size, void* d_ws, size_t ws_size,
                              hipStream_t stream) {
  const float* x  = (const float*)d_in[0];
  const float* wq = (const float*)d_in[1];
  const float* wk = (const float*)d_in[2];
  const float* wv = (const float*)d_in[3];
  const float* wo = (const float*)d_in[4];

  char* ws = (char*)d_ws;
  const size_t MB = 1024 * 1024;
  bf16* xb   = (bf16*)(ws + 0);        // 8 MB (reused as vtb after QKV GEMM)
  bf16* wqb  = (bf16*)(ws + 8 * MB);   // wq,wk,wv,wo contiguous (2 MB each)
  bf16* wob  = (bf16*)(ws + 14 * MB);
  bf16* qb   = (bf16*)(ws + 16 * MB);  // Q [bh][s][64]
  bf16* kb   = (bf16*)(ws + 24 * MB);  // K [bh][s][64]
  bf16* vb   = (bf16*)(ws + 32 * MB);  // V [bh][s][64]
  bf16* ob   = (bf16*)(ws + 40 * MB);  // attention output [B][S][D]
  float* cosT = (float*)(ws + 48 * MB);
  float* sinT = (float*)(ws + 49 * MB);
  bf16* vtb  = xb;  // V transposed [bh][64][S], overwrites xb (free after QKV GEMM)

  const int NX = BDIM * SDIM * DDIM;  // 4194304
  const int NW = DDIM * DDIM;         // 1048576

  cvt_bf16<<<NX / 4 / 256, 256, 0, stream>>>(x, xb, NX / 4);
  Ptr4 wsrc{{wq, wk, wv, wo}};
  cvt_w<<<dim3(NW / 4 / 256, 4), 256, 0, stream>>>(wsrc, wqb);
  rope_table<<<(SDIM * 32) / 256, 256, 0, stream>>>(cosT, sinT);
  gemm_bt<0><<<dim3(8, 32, 3), 256, 0, stream>>>(xb, wqb, (void*)qb);
  fixup_qkv<<<dim3(SDIM / 32, 32), 256, 0, stream>>>(qb, kb, (const unsigned short*)vb,
                                                     (unsigned short*)vtb, cosT, sinT);
  attn_fwd<<<dim3(32, 32), 512, 0, stream>>>(qb, kb, vtb, ob);
  gemm_bt<1><<<dim3(8, 32, 1), 256, 0, stream>>>(ob, wob, d_out);
}